// Round 1
// baseline (6507.516 us; speedup 1.0000x reference)
//
#include <hip/hip_runtime.h>
#include <math.h>

#define B_   512
#define H_   512
#define FIN_ 1024
#define TS_  128
#define NG   6

// ---------------- weight repack (once per call) ----------------
// Wp[g][k][j] = (g<3 ? W_ih[(g*H+j)][k] : W_hh[((g-3)*H+j)][k]),  [6][512][512]
__global__ void transpose_gate(const float* __restrict__ Wih,
                               const float* __restrict__ Whh,
                               float* __restrict__ Wp) {
    __shared__ float t[32][33];
    int g  = blockIdx.z;
    int j0 = blockIdx.x * 32, k0 = blockIdx.y * 32;
    const float* src = (g < 3) ? (Wih + (size_t)g * H_ * H_)
                               : (Whh + (size_t)(g - 3) * H_ * H_);
    int kk = threadIdx.x, jj = threadIdx.y;
#pragma unroll
    for (int r = 0; r < 32; r += 8)
        t[jj + r][kk] = src[(size_t)(j0 + jj + r) * H_ + k0 + kk];
    __syncthreads();
#pragma unroll
    for (int r = 0; r < 32; r += 8)
        Wp[((size_t)g * H_ + k0 + jj + r) * H_ + j0 + kk] = t[kk][jj + r];
}

// WlinT[k][j] = W_lin[j][k], [1024][512]
__global__ void transpose_lin(const float* __restrict__ Wlin,
                              float* __restrict__ Wt) {
    __shared__ float t[32][33];
    int j0 = blockIdx.x * 32, k0 = blockIdx.y * 32;
    int kk = threadIdx.x, jj = threadIdx.y;
#pragma unroll
    for (int r = 0; r < 32; r += 8)
        t[jj + r][kk] = Wlin[(size_t)(j0 + jj + r) * FIN_ + k0 + kk];
    __syncthreads();
#pragma unroll
    for (int r = 0; r < 32; r += 8)
        Wt[(size_t)(k0 + jj + r) * H_ + j0 + kk] = t[kk][jj + r];
}

// ---------------- h0 = x @ WlinT + b_lin ----------------
__global__ __launch_bounds__(256)
void gemm_h0(const float* __restrict__ X, const float* __restrict__ Wt,
             const float* __restrict__ bias, float* __restrict__ Hout) {
    const int BM = 32, BN = 32, BK = 32;
    __shared__ float xs[BK][BM + 2];
    __shared__ float ws[BK][BN];
    int b0 = blockIdx.y * BM, j0 = blockIdx.x * BN;
    int tid = threadIdx.x;
    int tx = tid & 15, ty = tid >> 4;
    float acc[2][2] = {};
    for (int k0 = 0; k0 < FIN_; k0 += BK) {
#pragma unroll
        for (int l = 0; l < 2; ++l) {            // xs[k][b], 32x32
            int e = tid + l * 256;
            int krel = (e & 15) * 2, brel = e >> 4;
            float2 v = *(const float2*)&X[(size_t)(b0 + brel) * FIN_ + k0 + krel];
            xs[krel][brel] = v.x; xs[krel + 1][brel] = v.y;
        }
        {                                        // ws[k][j], 32x32
            int fe = tid;
            int j4 = fe & 7, krel = fe >> 3;
            *(float4*)&ws[krel][j4 * 4] =
                *(const float4*)&Wt[(size_t)(k0 + krel) * H_ + j0 + j4 * 4];
        }
        __syncthreads();
#pragma unroll
        for (int kk = 0; kk < BK; ++kk) {
            float2 a = *(const float2*)&xs[kk][ty * 2];
            float2 w = *(const float2*)&ws[kk][tx * 2];
            acc[0][0] += a.x * w.x; acc[0][1] += a.x * w.y;
            acc[1][0] += a.y * w.x; acc[1][1] += a.y * w.y;
        }
        __syncthreads();
    }
#pragma unroll
    for (int r = 0; r < 2; ++r)
#pragma unroll
        for (int c = 0; c < 2; ++c) {
            int b = b0 + ty * 2 + r, j = j0 + tx * 2 + c;
            Hout[(size_t)b * H_ + j] = acc[r][c] + bias[j];
        }
}

// ---------------- fused GRU step ----------------
// FIRST=1: xi == 0  -> gi = b_ih only (skip gates 0..2 GEMM)
// FIRST=0: xi == h  -> all 6 gates from the same Hprev
template <int FIRST>
__global__ __launch_bounds__(256)
void step_kernel(const float* __restrict__ Hprev,
                 const float* __restrict__ Wp,
                 const float* __restrict__ bp,
                 float* __restrict__ Hnext,
                 float* __restrict__ Out /* = d_out + t*H_ */) {
    const int BM = 32, BN = 32, BK = 32;
    __shared__ float hs[BK][BM + 2];
    __shared__ float ws[NG][BK][BN];
    int b0 = blockIdx.y * BM, j0 = blockIdx.x * BN;
    int tid = threadIdx.x;
    int tx = tid & 15, ty = tid >> 4;
    const int G0 = FIRST ? 3 : 0;
    float acc[6][2][2] = {};
    for (int k0 = 0; k0 < H_; k0 += BK) {
#pragma unroll
        for (int l = 0; l < 2; ++l) {            // hs[k][b] transposed stage
            int e = tid + l * 256;
            int krel = (e & 15) * 2, brel = e >> 4;
            float2 v = *(const float2*)&Hprev[(size_t)(b0 + brel) * H_ + k0 + krel];
            hs[krel][brel] = v.x; hs[krel + 1][brel] = v.y;
        }
#pragma unroll
        for (int l = 0; l < 6; ++l) {            // ws[g][k][j]
            int fe = tid + l * 256;              // 0..1535
            int j4 = fe & 7, krel = (fe >> 3) & 31, g = fe >> 8;
            if (!FIRST || g >= 3)
                *(float4*)&ws[g][krel][j4 * 4] =
                    *(const float4*)&Wp[((size_t)g * H_ + k0 + krel) * H_ + j0 + j4 * 4];
        }
        __syncthreads();
#pragma unroll
        for (int kk = 0; kk < BK; ++kk) {
            float2 a = *(const float2*)&hs[kk][ty * 2];
#pragma unroll
            for (int g = G0; g < 6; ++g) {
                float2 w = *(const float2*)&ws[g][kk][tx * 2];
                acc[g][0][0] += a.x * w.x; acc[g][0][1] += a.x * w.y;
                acc[g][1][0] += a.y * w.x; acc[g][1][1] += a.y * w.y;
            }
        }
        __syncthreads();
    }
    // epilogue: gate math
#pragma unroll
    for (int r = 0; r < 2; ++r) {
        int b = b0 + ty * 2 + r;
#pragma unroll
        for (int c = 0; c < 2; ++c) {
            int j = j0 + tx * 2 + c;
            float ir  = acc[0][r][c] + bp[0 * H_ + j];
            float iz  = acc[1][r][c] + bp[1 * H_ + j];
            float in_ = acc[2][r][c] + bp[2 * H_ + j];
            float hr  = acc[3][r][c] + bp[3 * H_ + j];
            float hz  = acc[4][r][c] + bp[4 * H_ + j];
            float hn  = acc[5][r][c] + bp[5 * H_ + j];
            float rg = 1.f / (1.f + expf(-(ir + hr)));
            float zg = 1.f / (1.f + expf(-(iz + hz)));
            float ng = tanhf(in_ + rg * hn);
            float hp = Hprev[(size_t)b * H_ + j];
            float hnew = (1.f - zg) * ng + zg * hp;
            Hnext[(size_t)b * H_ + j] = hnew;
            Out[(size_t)b * (TS_ * H_) + j] = hnew;
        }
    }
}

extern "C" void kernel_launch(void* const* d_in, const int* in_sizes, int n_in,
                              void* d_out, int out_size, void* d_ws, size_t ws_size,
                              hipStream_t stream) {
    const float* x     = (const float*)d_in[0];
    const float* W_lin = (const float*)d_in[1];
    const float* b_lin = (const float*)d_in[2];
    const float* W_ih  = (const float*)d_in[3];
    const float* W_hh  = (const float*)d_in[4];
    const float* b_ih  = (const float*)d_in[5];
    const float* b_hh  = (const float*)d_in[6];
    float* out = (float*)d_out;

    char* wsb = (char*)d_ws;
    float* Wp    = (float*)(wsb);                  // 6*512*512 f32 = 6291456 B
    float* WlinT = (float*)(wsb + 6291456);        // 1024*512 f32 = 2097152 B
    float* bp    = (float*)(wsb + 8388608);        // 3072 f32 = 12288 B
    float* hA    = (float*)(wsb + 8400896);        // 512*512 f32
    float* hB    = (float*)(wsb + 9449472);        // 512*512 f32

    // bias concat: bp = [b_ih(1536), b_hh(1536)]
    hipMemcpyAsync(bp,        b_ih, 1536 * sizeof(float), hipMemcpyDeviceToDevice, stream);
    hipMemcpyAsync(bp + 1536, b_hh, 1536 * sizeof(float), hipMemcpyDeviceToDevice, stream);

    transpose_gate<<<dim3(16, 16, 6), dim3(32, 8), 0, stream>>>(W_ih, W_hh, Wp);
    transpose_lin <<<dim3(16, 32),    dim3(32, 8), 0, stream>>>(W_lin, WlinT);

    gemm_h0<<<dim3(16, 16), 256, 0, stream>>>(x, WlinT, b_lin, hA);

    // step 0: xi = 0
    step_kernel<1><<<dim3(16, 16), 256, 0, stream>>>(hA, Wp, bp, hB, out + 0);
    float* cur = hB;
    float* nxt = hA;
    for (int t = 1; t < TS_; ++t) {
        step_kernel<0><<<dim3(16, 16), 256, 0, stream>>>(cur, Wp, bp, nxt,
                                                         out + (size_t)t * H_);
        float* tmp = cur; cur = nxt; nxt = tmp;
    }
}

// Round 3
// 3191.915 us; speedup vs baseline: 2.0387x; 2.0387x over previous
//
#include <hip/hip_runtime.h>
#include <hip/hip_bf16.h>
#include <math.h>

#define B_   512
#define H_   512
#define FIN_ 1024
#define TS_  128

typedef __attribute__((ext_vector_type(8))) short short8;
typedef __attribute__((ext_vector_type(4))) float f32x4;

static __device__ __forceinline__ short f2bf(float f) {
    __hip_bfloat16 b = __float2bfloat16(f);
    return __builtin_bit_cast(short, b);
}
static __device__ __forceinline__ float bf2f(short s) {
    unsigned int u = ((unsigned int)(unsigned short)s) << 16;
    return __builtin_bit_cast(float, u);
}

// ---------------- weight prepack (once per call) ----------------
// Wpk2 fragment-packed bf16 pairs:
//   [jt 0..31][kt 0..15][g 0..5][sel 0..1 (hi/lo)][lane 0..63][i 0..7]
// B-frag (16x16x32): lane holds B[k = kt*32 + (lane>>4)*8 + i][j = jt*16 + (lane&15)]
// source: g<3 -> W_ih[g*512 + j][k]; g>=3 -> W_hh[(g-3)*512 + j][k]
__global__ __launch_bounds__(384)
void pack_weights(const float* __restrict__ Wih, const float* __restrict__ Whh,
                  short* __restrict__ Wpk2) {
    int jt = blockIdx.x;              // 0..31
    int kt = blockIdx.y;              // 0..15
    int g    = threadIdx.x >> 6;      // 0..5
    int lane = threadIdx.x & 63;
    int j = jt * 16 + (lane & 15);
    int k = kt * 32 + (lane >> 4) * 8;
    const float* src = (g < 3) ? &Wih[(size_t)(g * H_ + j) * H_ + k]
                               : &Whh[(size_t)((g - 3) * H_ + j) * H_ + k];
    short8 vhi, vlo;
#pragma unroll
    for (int i = 0; i < 8; ++i) {
        float w  = src[i];
        short hi = f2bf(w);
        vhi[i] = hi;
        vlo[i] = f2bf(w - bf2f(hi));
    }
    size_t base = ((((size_t)(jt * 16 + kt) * 6 + g) * 2) * 64 + lane) * 8;
    *reinterpret_cast<short8*>(&Wpk2[base])       = vhi;
    *reinterpret_cast<short8*>(&Wpk2[base + 512]) = vlo;
}

// WlinT[k][j] = W_lin[j][k], [1024][512]
__global__ void transpose_lin(const float* __restrict__ Wlin,
                              float* __restrict__ Wt) {
    __shared__ float t[32][33];
    int j0 = blockIdx.x * 32, k0 = blockIdx.y * 32;
    int kk = threadIdx.x, jj = threadIdx.y;
#pragma unroll
    for (int r = 0; r < 32; r += 8)
        t[jj + r][kk] = Wlin[(size_t)(j0 + jj + r) * FIN_ + k0 + kk];
    __syncthreads();
#pragma unroll
    for (int r = 0; r < 32; r += 8)
        Wt[(size_t)(k0 + jj + r) * H_ + j0 + kk] = t[kk][jj + r];
}

// ---------------- h0 = x @ WlinT + b_lin  (fp32, writes hi/lo bf16 split) ----------------
__global__ __launch_bounds__(256)
void gemm_h0(const float* __restrict__ X, const float* __restrict__ Wt,
             const float* __restrict__ bias,
             short* __restrict__ Hhi, short* __restrict__ Hlo) {
    const int BM = 32, BN = 32, BK = 32;
    __shared__ float xs[BK][BM + 2];
    __shared__ float ws[BK][BN];
    int b0 = blockIdx.y * BM, j0 = blockIdx.x * BN;
    int tid = threadIdx.x;
    int tx = tid & 15, ty = tid >> 4;
    float acc[2][2] = {};
    for (int k0 = 0; k0 < FIN_; k0 += BK) {
#pragma unroll
        for (int l = 0; l < 2; ++l) {
            int e = tid + l * 256;
            int krel = (e & 15) * 2, brel = e >> 4;
            float2 v = *(const float2*)&X[(size_t)(b0 + brel) * FIN_ + k0 + krel];
            xs[krel][brel] = v.x; xs[krel + 1][brel] = v.y;
        }
        {
            int fe = tid;
            int j4 = fe & 7, krel = fe >> 3;
            *(float4*)&ws[krel][j4 * 4] =
                *(const float4*)&Wt[(size_t)(k0 + krel) * H_ + j0 + j4 * 4];
        }
        __syncthreads();
#pragma unroll
        for (int kk = 0; kk < BK; ++kk) {
            float2 a = *(const float2*)&xs[kk][ty * 2];
            float2 w = *(const float2*)&ws[kk][tx * 2];
            acc[0][0] += a.x * w.x; acc[0][1] += a.x * w.y;
            acc[1][0] += a.y * w.x; acc[1][1] += a.y * w.y;
        }
        __syncthreads();
    }
#pragma unroll
    for (int r = 0; r < 2; ++r)
#pragma unroll
        for (int c = 0; c < 2; ++c) {
            int b = b0 + ty * 2 + r, j = j0 + tx * 2 + c;
            float v = acc[r][c] + bias[j];
            short hi = f2bf(v);
            Hhi[(size_t)b * H_ + j] = hi;
            Hlo[(size_t)b * H_ + j] = f2bf(v - bf2f(hi));
        }
}

// ---------------- fused GRU step, split-precision MFMA bf16 ----------------
// One wave per block; wave owns 64 rows x 16 cols, all 6 gates.
// acc += a_hi*b_hi + a_hi*b_lo + a_lo*b_hi  (lo*lo dropped, ~2^-18 rel)
// A frag: lane holds H[m0 + 16*mf + (lane&15)][kt*32 + (lane>>4)*8 + i]
// C frag: col = lane&15, row = (lane>>4)*4 + v
template <int FIRST>
__global__ __launch_bounds__(64)
void step_mfma(const short* __restrict__ Hhi, const short* __restrict__ Hlo,
               const short* __restrict__ Wpk2,
               const float* __restrict__ bp,    // [3072] = [b_ih; b_hh]
               short* __restrict__ NHhi, short* __restrict__ NHlo,
               float* __restrict__ Out /* = d_out + t*H_ */) {
    int jt   = blockIdx.x;            // 0..31
    int m0   = blockIdx.y * 64;       // 0..448
    int lane = threadIdx.x;

    f32x4 acc[4][6] = {};
    int arow0 = m0 + (lane & 15);
    int akoff = (lane >> 4) * 8;

#pragma unroll 2
    for (int kt = 0; kt < 16; ++kt) {
        short8 ahi[4], alo[4];
#pragma unroll
        for (int mf = 0; mf < 4; ++mf) {
            size_t off = (size_t)(arow0 + 16 * mf) * H_ + kt * 32 + akoff;
            ahi[mf] = *(const short8*)&Hhi[off];
            alo[mf] = *(const short8*)&Hlo[off];
        }
        const short* wb = &Wpk2[(((size_t)(jt * 16 + kt)) * 6) * 1024 + lane * 8];
#pragma unroll
        for (int g = (FIRST ? 3 : 0); g < 6; ++g) {
            short8 bhi = *(const short8*)&wb[(size_t)g * 1024];
            short8 blo = *(const short8*)&wb[(size_t)g * 1024 + 512];
#pragma unroll
            for (int mf = 0; mf < 4; ++mf) {
                acc[mf][g] = __builtin_amdgcn_mfma_f32_16x16x32_bf16(ahi[mf], bhi, acc[mf][g], 0, 0, 0);
                acc[mf][g] = __builtin_amdgcn_mfma_f32_16x16x32_bf16(ahi[mf], blo, acc[mf][g], 0, 0, 0);
                acc[mf][g] = __builtin_amdgcn_mfma_f32_16x16x32_bf16(alo[mf], bhi, acc[mf][g], 0, 0, 0);
            }
        }
    }

    int c = jt * 16 + (lane & 15);
    float b0 = bp[0 * H_ + c], b1 = bp[1 * H_ + c], b2 = bp[2 * H_ + c];
    float b3 = bp[3 * H_ + c], b4 = bp[4 * H_ + c], b5 = bp[5 * H_ + c];
#pragma unroll
    for (int mf = 0; mf < 4; ++mf) {
#pragma unroll
        for (int v = 0; v < 4; ++v) {
            int r = m0 + mf * 16 + (lane >> 4) * 4 + v;
            float ir  = acc[mf][0][v] + b0;
            float iz  = acc[mf][1][v] + b1;
            float in_ = acc[mf][2][v] + b2;
            float hr  = acc[mf][3][v] + b3;
            float hz  = acc[mf][4][v] + b4;
            float hn  = acc[mf][5][v] + b5;
            float rg = 1.f / (1.f + expf(-(ir + hr)));
            float zg = 1.f / (1.f + expf(-(iz + hz)));
            float ng = tanhf(in_ + rg * hn);
            size_t idx = (size_t)r * H_ + c;
            float hp = bf2f(Hhi[idx]) + bf2f(Hlo[idx]);
            float hnew = (1.f - zg) * ng + zg * hp;
            short hi = f2bf(hnew);
            NHhi[idx] = hi;
            NHlo[idx] = f2bf(hnew - bf2f(hi));
            Out[(size_t)r * (TS_ * H_) + c] = hnew;
        }
    }
}

extern "C" void kernel_launch(void* const* d_in, const int* in_sizes, int n_in,
                              void* d_out, int out_size, void* d_ws, size_t ws_size,
                              hipStream_t stream) {
    const float* x     = (const float*)d_in[0];
    const float* W_lin = (const float*)d_in[1];
    const float* b_lin = (const float*)d_in[2];
    const float* W_ih  = (const float*)d_in[3];
    const float* W_hh  = (const float*)d_in[4];
    const float* b_ih  = (const float*)d_in[5];
    const float* b_hh  = (const float*)d_in[6];
    float* out = (float*)d_out;

    char* wsb = (char*)d_ws;
    short* Wpk2  = (short*)(wsb);                    // 6*512*512*2 bf16 = 6291456 B
    float* WlinT = (float*)(wsb + 6291456);          // 1024*512 f32     = 2097152 B
    float* bp    = (float*)(wsb + 8388608);          // 3072 f32         = 12288 B
    short* hHiA  = (short*)(wsb + 8400896);          // 512*512 bf16     = 524288 B
    short* hLoA  = (short*)(wsb + 8925184);
    short* hHiB  = (short*)(wsb + 9449472);
    short* hLoB  = (short*)(wsb + 9973760);          // end @ 10498048 B

    hipMemcpyAsync(bp,        b_ih, 1536 * sizeof(float), hipMemcpyDeviceToDevice, stream);
    hipMemcpyAsync(bp + 1536, b_hh, 1536 * sizeof(float), hipMemcpyDeviceToDevice, stream);

    pack_weights <<<dim3(32, 16), 384, 0, stream>>>(W_ih, W_hh, Wpk2);
    transpose_lin<<<dim3(16, 32), dim3(32, 8), 0, stream>>>(W_lin, WlinT);

    gemm_h0<<<dim3(16, 16), 256, 0, stream>>>(x, WlinT, b_lin, hHiA, hLoA);

    // step 0: xi = 0 -> gi = b_ih only
    step_mfma<1><<<dim3(32, 8), 64, 0, stream>>>(hHiA, hLoA, Wpk2, bp, hHiB, hLoB, out + 0);

    short* curHi = hHiB; short* curLo = hLoB;
    short* nxtHi = hHiA; short* nxtLo = hLoA;
    for (int t = 1; t < TS_; ++t) {
        step_mfma<0><<<dim3(32, 8), 64, 0, stream>>>(curHi, curLo, Wpk2, bp,
                                                     nxtHi, nxtLo,
                                                     out + (size_t)t * H_);
        short* th = curHi; curHi = nxtHi; nxtHi = th;
        short* tl = curLo; curLo = nxtLo; nxtLo = tl;
    }
}

// Round 4
// 2319.514 us; speedup vs baseline: 2.8056x; 1.3761x over previous
//
#include <hip/hip_runtime.h>
#include <hip/hip_bf16.h>
#include <math.h>

#define B_   512
#define H_   512
#define FIN_ 1024
#define TS_  128

typedef __attribute__((ext_vector_type(8))) short short8;
typedef __attribute__((ext_vector_type(4))) float f32x4;

static __device__ __forceinline__ short f2bf(float f) {
    __hip_bfloat16 b = __float2bfloat16(f);
    return __builtin_bit_cast(short, b);
}
static __device__ __forceinline__ float bf2f(short s) {
    unsigned int u = ((unsigned int)(unsigned short)s) << 16;
    return __builtin_bit_cast(float, u);
}

// ---------------- weight prepack (once per call) ----------------
// Wpk2 fragment-packed bf16 pairs:
//   [jt 0..31][kt 0..15][g 0..5][sel 0..1 (hi/lo)][lane 0..63][i 0..7]
// B-frag (16x16x32): lane holds B[k = kt*32 + (lane>>4)*8 + i][j = jt*16 + (lane&15)]
// source: g<3 -> W_ih[g*512 + j][k]; g>=3 -> W_hh[(g-3)*512 + j][k]
__global__ __launch_bounds__(384)
void pack_weights(const float* __restrict__ Wih, const float* __restrict__ Whh,
                  short* __restrict__ Wpk2) {
    int jt = blockIdx.x;              // 0..31
    int kt = blockIdx.y;              // 0..15
    int g    = threadIdx.x >> 6;      // 0..5
    int lane = threadIdx.x & 63;
    int j = jt * 16 + (lane & 15);
    int k = kt * 32 + (lane >> 4) * 8;
    const float* src = (g < 3) ? &Wih[(size_t)(g * H_ + j) * H_ + k]
                               : &Whh[(size_t)((g - 3) * H_ + j) * H_ + k];
    short8 vhi, vlo;
#pragma unroll
    for (int i = 0; i < 8; ++i) {
        float w  = src[i];
        short hi = f2bf(w);
        vhi[i] = hi;
        vlo[i] = f2bf(w - bf2f(hi));
    }
    size_t base = ((((size_t)(jt * 16 + kt) * 6 + g) * 2) * 64 + lane) * 8;
    *reinterpret_cast<short8*>(&Wpk2[base])       = vhi;
    *reinterpret_cast<short8*>(&Wpk2[base + 512]) = vlo;
}

// WlinT[k][j] = W_lin[j][k], [1024][512]
__global__ void transpose_lin(const float* __restrict__ Wlin,
                              float* __restrict__ Wt) {
    __shared__ float t[32][33];
    int j0 = blockIdx.x * 32, k0 = blockIdx.y * 32;
    int kk = threadIdx.x, jj = threadIdx.y;
#pragma unroll
    for (int r = 0; r < 32; r += 8)
        t[jj + r][kk] = Wlin[(size_t)(j0 + jj + r) * FIN_ + k0 + kk];
    __syncthreads();
#pragma unroll
    for (int r = 0; r < 32; r += 8)
        Wt[(size_t)(k0 + jj + r) * H_ + j0 + kk] = t[kk][jj + r];
}

// ---------------- h0 = x @ WlinT + b_lin  (fp32, writes hi/lo bf16 split) ----------------
__global__ __launch_bounds__(256)
void gemm_h0(const float* __restrict__ X, const float* __restrict__ Wt,
             const float* __restrict__ bias,
             short* __restrict__ Hhi, short* __restrict__ Hlo) {
    const int BM = 32, BN = 32, BK = 32;
    __shared__ float xs[BK][BM + 2];
    __shared__ float ws[BK][BN];
    int b0 = blockIdx.y * BM, j0 = blockIdx.x * BN;
    int tid = threadIdx.x;
    int tx = tid & 15, ty = tid >> 4;
    float acc[2][2] = {};
    for (int k0 = 0; k0 < FIN_; k0 += BK) {
#pragma unroll
        for (int l = 0; l < 2; ++l) {
            int e = tid + l * 256;
            int krel = (e & 15) * 2, brel = e >> 4;
            float2 v = *(const float2*)&X[(size_t)(b0 + brel) * FIN_ + k0 + krel];
            xs[krel][brel] = v.x; xs[krel + 1][brel] = v.y;
        }
        {
            int fe = tid;
            int j4 = fe & 7, krel = fe >> 3;
            *(float4*)&ws[krel][j4 * 4] =
                *(const float4*)&Wt[(size_t)(k0 + krel) * H_ + j0 + j4 * 4];
        }
        __syncthreads();
#pragma unroll
        for (int kk = 0; kk < BK; ++kk) {
            float2 a = *(const float2*)&xs[kk][ty * 2];
            float2 w = *(const float2*)&ws[kk][tx * 2];
            acc[0][0] += a.x * w.x; acc[0][1] += a.x * w.y;
            acc[1][0] += a.y * w.x; acc[1][1] += a.y * w.y;
        }
        __syncthreads();
    }
#pragma unroll
    for (int r = 0; r < 2; ++r)
#pragma unroll
        for (int c = 0; c < 2; ++c) {
            int b = b0 + ty * 2 + r, j = j0 + tx * 2 + c;
            float v = acc[r][c] + bias[j];
            short hi = f2bf(v);
            Hhi[(size_t)b * H_ + j] = hi;
            Hlo[(size_t)b * H_ + j] = f2bf(v - bf2f(hi));
        }
}

// ---------------- fused GRU step, split-precision MFMA bf16 ----------------
// Block = 4 waves (256 thr). Wave w owns 16 rows x 16 cols, all 6 gates.
// All 4 waves share the same B fragments (same jt) -> L1 serves 3/4.
// acc += a_hi*b_hi + a_hi*b_lo + a_lo*b_hi  (lo*lo dropped, ~2^-18 rel)
// A frag: lane holds H[row0 + (lane&15)][kt*32 + (lane>>4)*8 + i]
// C frag: col = lane&15, row = (lane>>4)*4 + v
template <int FIRST>
__global__ __launch_bounds__(256)
void step_mfma(const short* __restrict__ Hhi, const short* __restrict__ Hlo,
               const short* __restrict__ Wpk2,
               const float* __restrict__ bp,    // [3072] = [b_ih; b_hh]
               short* __restrict__ NHhi, short* __restrict__ NHlo,
               float* __restrict__ Out /* = d_out + t*H_ */) {
    int jt   = blockIdx.x;                        // 0..31
    int wave = threadIdx.x >> 6;                  // 0..3
    int lane = threadIdx.x & 63;
    int m0   = blockIdx.y * 64 + wave * 16;       // wave's 16-row slice

    f32x4 acc[6] = {};
    int arow  = m0 + (lane & 15);
    int akoff = (lane >> 4) * 8;

#pragma unroll 4
    for (int kt = 0; kt < 16; ++kt) {
        size_t aoff = (size_t)arow * H_ + kt * 32 + akoff;
        short8 ahi = *(const short8*)&Hhi[aoff];
        short8 alo = *(const short8*)&Hlo[aoff];
        const short* wb = &Wpk2[(((size_t)(jt * 16 + kt)) * 6) * 1024 + lane * 8];
#pragma unroll
        for (int g = (FIRST ? 3 : 0); g < 6; ++g) {
            short8 bhi = *(const short8*)&wb[(size_t)g * 1024];
            short8 blo = *(const short8*)&wb[(size_t)g * 1024 + 512];
            acc[g] = __builtin_amdgcn_mfma_f32_16x16x32_bf16(ahi, bhi, acc[g], 0, 0, 0);
            acc[g] = __builtin_amdgcn_mfma_f32_16x16x32_bf16(ahi, blo, acc[g], 0, 0, 0);
            acc[g] = __builtin_amdgcn_mfma_f32_16x16x32_bf16(alo, bhi, acc[g], 0, 0, 0);
        }
    }

    int c = jt * 16 + (lane & 15);
    float b0 = bp[0 * H_ + c], b1 = bp[1 * H_ + c], b2 = bp[2 * H_ + c];
    float b3 = bp[3 * H_ + c], b4 = bp[4 * H_ + c], b5 = bp[5 * H_ + c];
#pragma unroll
    for (int v = 0; v < 4; ++v) {
        int r = m0 + (lane >> 4) * 4 + v;
        float ir  = acc[0][v] + b0;
        float iz  = acc[1][v] + b1;
        float in_ = acc[2][v] + b2;
        float hr  = acc[3][v] + b3;
        float hz  = acc[4][v] + b4;
        float hn  = acc[5][v] + b5;
        float rg = 1.f / (1.f + expf(-(ir + hr)));
        float zg = 1.f / (1.f + expf(-(iz + hz)));
        float ng = tanhf(in_ + rg * hn);
        size_t idx = (size_t)r * H_ + c;
        float hp = bf2f(Hhi[idx]) + bf2f(Hlo[idx]);
        float hnew = (1.f - zg) * ng + zg * hp;
        short hi = f2bf(hnew);
        NHhi[idx] = hi;
        NHlo[idx] = f2bf(hnew - bf2f(hi));
        Out[(size_t)r * (TS_ * H_) + c] = hnew;
    }
}

extern "C" void kernel_launch(void* const* d_in, const int* in_sizes, int n_in,
                              void* d_out, int out_size, void* d_ws, size_t ws_size,
                              hipStream_t stream) {
    const float* x     = (const float*)d_in[0];
    const float* W_lin = (const float*)d_in[1];
    const float* b_lin = (const float*)d_in[2];
    const float* W_ih  = (const float*)d_in[3];
    const float* W_hh  = (const float*)d_in[4];
    const float* b_ih  = (const float*)d_in[5];
    const float* b_hh  = (const float*)d_in[6];
    float* out = (float*)d_out;

    char* wsb = (char*)d_ws;
    short* Wpk2  = (short*)(wsb);                    // 6*512*512*2 bf16 = 6291456 B
    float* WlinT = (float*)(wsb + 6291456);          // 1024*512 f32     = 2097152 B
    float* bp    = (float*)(wsb + 8388608);          // 3072 f32         = 12288 B
    short* hHiA  = (short*)(wsb + 8400896);          // 512*512 bf16     = 524288 B
    short* hLoA  = (short*)(wsb + 8925184);
    short* hHiB  = (short*)(wsb + 9449472);
    short* hLoB  = (short*)(wsb + 9973760);          // end @ 10498048 B

    hipMemcpyAsync(bp,        b_ih, 1536 * sizeof(float), hipMemcpyDeviceToDevice, stream);
    hipMemcpyAsync(bp + 1536, b_hh, 1536 * sizeof(float), hipMemcpyDeviceToDevice, stream);

    pack_weights <<<dim3(32, 16), 384, 0, stream>>>(W_ih, W_hh, Wpk2);
    transpose_lin<<<dim3(16, 32), dim3(32, 8), 0, stream>>>(W_lin, WlinT);

    gemm_h0<<<dim3(16, 16), 256, 0, stream>>>(x, WlinT, b_lin, hHiA, hLoA);

    // step 0: xi = 0 -> gi = b_ih only
    step_mfma<1><<<dim3(32, 8), 256, 0, stream>>>(hHiA, hLoA, Wpk2, bp, hHiB, hLoB, out + 0);

    short* curHi = hHiB; short* curLo = hLoB;
    short* nxtHi = hHiA; short* nxtLo = hLoA;
    for (int t = 1; t < TS_; ++t) {
        step_mfma<0><<<dim3(32, 8), 256, 0, stream>>>(curHi, curLo, Wpk2, bp,
                                                      nxtHi, nxtLo,
                                                      out + (size_t)t * H_);
        short* th = curHi; curHi = nxtHi; nxtHi = th;
        short* tl = curLo; curLo = nxtLo; nxtLo = tl;
    }
}